// Round 8
// baseline (19555.292 us; speedup 1.0000x reference)
//
#include <hip/hip_runtime.h>

// ContinuousThoughtMachineReLU  (B=32, C=512, N=1024, E=512, D=2048, H=8, hd=64,
//                                T=50, O=1000, NA=512, NO=512)
//
// Round 8: r7 showed time tracks coherence-path traffic at ~1TB/s (188MB/step,
// 184us/step) with 6M atomicAdd RMWs/step. Fix: NO split-K anywhere.
// C/E/F become (32 b-rows x 32 j-chunks) with full-K per block: each block
// stages only its own 8-10KB A-row, weights come from per-XCD L2 (normal
// loads), output is one plain 16B store. Phase B2 combines softmax partials
// ONCE; phase B precomputes relu(act+b2) once. Zero atomics, zero zeroing.
// Predicted ~95MB/step through the coherent path.

typedef unsigned short u16;
typedef unsigned int uv4 __attribute__((ext_vector_type(4)));   // nt-loadable
typedef float fv4 __attribute__((ext_vector_type(4)));
typedef float fv2 __attribute__((ext_vector_type(2)));

__device__ __forceinline__ float bf2f(u16 u) {
    return __uint_as_float(((unsigned int)u) << 16);
}
__device__ __forceinline__ float bflo(unsigned int u) { return __uint_as_float(u << 16); }
__device__ __forceinline__ float bfhi(unsigned int u) { return __uint_as_float(u & 0xffff0000u); }
__device__ __forceinline__ u16 f2bf(float f) {
    unsigned int u = __float_as_uint(f);
    unsigned int r = u + 0x7fffu + ((u >> 16) & 1u);
    return (u16)(r >> 16);
}

// ---- coherence-point (L2-bypassing) wide accessors: sc0 sc1 ----
__device__ __forceinline__ void cload(fv4& r, const void* p) {
    asm volatile("global_load_dwordx4 %0, %1, off sc0 sc1" : "=v"(r) : "v"(p));
}
__device__ __forceinline__ void cload2(fv2& r, const void* p) {
    asm volatile("global_load_dwordx2 %0, %1, off sc0 sc1" : "=v"(r) : "v"(p));
}
__device__ __forceinline__ void cstore4(void* p, fv4 v) {
    asm volatile("global_store_dwordx4 %0, %1, off sc0 sc1" :: "v"(p), "v"(v) : "memory");
}
__device__ __forceinline__ void cstore2(void* p, fv2 v) {
    asm volatile("global_store_dwordx2 %0, %1, off sc0 sc1" :: "v"(p), "v"(v) : "memory");
}
__device__ __forceinline__ void cwait1(fv4& a) {
    asm volatile("s_waitcnt vmcnt(0)" : "+v"(a) :: "memory");
    __builtin_amdgcn_sched_barrier(0);
}
__device__ __forceinline__ void cwait2(fv4& a, fv4& b) {
    asm volatile("s_waitcnt vmcnt(0)" : "+v"(a), "+v"(b) :: "memory");
    __builtin_amdgcn_sched_barrier(0);
}
__device__ __forceinline__ void cwaitf2(fv2& a) {
    asm volatile("s_waitcnt vmcnt(0)" : "+v"(a) :: "memory");
    __builtin_amdgcn_sched_barrier(0);
}

// agent-scope scalar accessors (for gathers only)
__device__ __forceinline__ float aload(const float* p) {
    return __hip_atomic_load((const float*)p, __ATOMIC_RELAXED, __HIP_MEMORY_SCOPE_AGENT);
}

// ---------------------------------------------------------------- init
__global__ __launch_bounds__(256) void k_init(
    const float* __restrict__ start_state, const float* __restrict__ dec_a,
    const float* __restrict__ dec_o,
    float* act0, float* aA, float* bA, float* aO, float* bO,
    float* r_a, float* r_o, unsigned* bar)
{
    int g = blockIdx.x * 256 + threadIdx.x;
    int T = gridDim.x * 256;
    for (int i = g; i < 32 * 2048; i += T) act0[i] = start_state[i & 2047];
    for (int i = g; i < 32 * 512; i += T) { aA[i] = 0.f; bA[i] = 0.f; aO[i] = 0.f; bO[i] = 0.f; }
    for (int i = g; i < 512; i += T) {
        float da = fminf(fmaxf(dec_a[i], 0.f), 15.f);
        float dv = fminf(fmaxf(dec_o[i], 0.f), 15.f);
        r_a[i] = __expf(-da);
        r_o[i] = __expf(-dv);
    }
    if (g < 2048) bar[g] = 0u;
}

// ------------------------------------------------- kv = x^T @ W_kv + b_kv (fp32 out)
__global__ __launch_bounds__(256) void k_gemm_xT(
    const float* __restrict__ x, const float* __restrict__ Wkv,
    const float* __restrict__ bkv, float* __restrict__ out)
{
    __shared__ float As[16 * 68];
    __shared__ float Bs[16 * 132];
    int tid = threadIdx.x;
    int tn = tid & 15, tm = tid >> 4;
    int n0 = blockIdx.x * 128;
    int r0 = blockIdx.y * 64;
    int b = r0 >> 10;
    int nrow0 = r0 & 1023;
    const float* xb = x + (size_t)b * 512 * 1024;
    float acc[4][8];
#pragma unroll
    for (int i = 0; i < 4; ++i)
#pragma unroll
        for (int j = 0; j < 8; ++j) acc[i][j] = 0.f;

    for (int k0 = 0; k0 < 512; k0 += 16) {
        __syncthreads();
#pragma unroll
        for (int l = 0; l < 4; ++l) {
            int i = tid + l * 256;
            int nn = i & 63, kk = i >> 6;
            As[kk * 68 + nn] = xb[(size_t)(k0 + kk) * 1024 + nrow0 + nn];
        }
#pragma unroll
        for (int l = 0; l < 8; ++l) {
            int i = tid + l * 256;
            int n = i & 127, kk = i >> 7;
            Bs[kk * 132 + n] = Wkv[(size_t)(k0 + kk) * 512 + n0 + n];
        }
        __syncthreads();
#pragma unroll
        for (int k = 0; k < 16; ++k) {
            float4 a4 = *(const float4*)&As[k * 68 + tm * 4];
            float4 b0 = *(const float4*)&Bs[k * 132 + tn * 8];
            float4 b1 = *(const float4*)&Bs[k * 132 + tn * 8 + 4];
            float av[4] = {a4.x, a4.y, a4.z, a4.w};
            float bv[8] = {b0.x, b0.y, b0.z, b0.w, b1.x, b1.y, b1.z, b1.w};
#pragma unroll
            for (int i = 0; i < 4; ++i)
#pragma unroll
                for (int j = 0; j < 8; ++j) acc[i][j] += av[i] * bv[j];
        }
    }
#pragma unroll
    for (int i = 0; i < 4; ++i) {
        int r = r0 + tm * 4 + i;
        int c = n0 + tn * 8;
        float* orow = out + (size_t)r * 512 + c;
#pragma unroll
        for (int j = 0; j < 8; ++j) orow[j] = acc[i][j] + bkv[c + j];
    }
}

// ------------------------------------------------ generic fp32 GEMM -> bf16 out, K=512
__global__ __launch_bounds__(256) void k_gemm_AB(
    const float* __restrict__ A, int lda,
    const float* __restrict__ B, int ldb,
    const float* __restrict__ bias,
    u16* __restrict__ out, int N)
{
    __shared__ float As[16 * 68];
    __shared__ float Bs[16 * 132];
    int tid = threadIdx.x;
    int tn = tid & 15, tm = tid >> 4;
    int n0 = blockIdx.x * 128;
    int r0 = blockIdx.y * 64;
    float acc[4][8];
#pragma unroll
    for (int i = 0; i < 4; ++i)
#pragma unroll
        for (int j = 0; j < 8; ++j) acc[i][j] = 0.f;

    for (int k0 = 0; k0 < 512; k0 += 16) {
        __syncthreads();
#pragma unroll
        for (int l = 0; l < 4; ++l) {
            int i = tid + l * 256;
            int kk = i & 15, m = i >> 4;
            As[kk * 68 + m] = A[(size_t)(r0 + m) * lda + k0 + kk];
        }
#pragma unroll
        for (int l = 0; l < 8; ++l) {
            int i = tid + l * 256;
            int n = i & 127, kk = i >> 7;
            Bs[kk * 132 + n] = B[(size_t)(k0 + kk) * ldb + n0 + n];
        }
        __syncthreads();
#pragma unroll
        for (int k = 0; k < 16; ++k) {
            float4 a4 = *(const float4*)&As[k * 68 + tm * 4];
            float4 b0 = *(const float4*)&Bs[k * 132 + tn * 8];
            float4 b1 = *(const float4*)&Bs[k * 132 + tn * 8 + 4];
            float av[4] = {a4.x, a4.y, a4.z, a4.w};
            float bv[8] = {b0.x, b0.y, b0.z, b0.w, b1.x, b1.y, b1.z, b1.w};
#pragma unroll
            for (int i = 0; i < 4; ++i)
#pragma unroll
                for (int j = 0; j < 8; ++j) acc[i][j] += av[i] * bv[j];
        }
    }
#pragma unroll
    for (int i = 0; i < 4; ++i) {
        int r = r0 + tm * 4 + i;
        int c = n0 + tn * 8;
        float vv[8];
#pragma unroll
        for (int j = 0; j < 8; ++j) vv[j] = acc[i][j] + (bias ? bias[c + j] : 0.f);
        unsigned int w0 = (unsigned int)f2bf(vv[0]) | ((unsigned int)f2bf(vv[1]) << 16);
        unsigned int w1 = (unsigned int)f2bf(vv[2]) | ((unsigned int)f2bf(vv[3]) << 16);
        unsigned int w2 = (unsigned int)f2bf(vv[4]) | ((unsigned int)f2bf(vv[5]) << 16);
        unsigned int w3 = (unsigned int)f2bf(vv[6]) | ((unsigned int)f2bf(vv[7]) << 16);
        *(uint4*)&out[(size_t)r * N + c] = make_uint4(w0, w1, w2, w3);
    }
}

// ------------------------------------------------- in-place LN over kv rows (512 wide)
__global__ __launch_bounds__(256) void k_ln_kv(
    float* __restrict__ kv, const float* __restrict__ g, const float* __restrict__ be)
{
    int tid = threadIdx.x;
    int lane = tid & 63;
    int row = blockIdx.x * 4 + (tid >> 6);
    float* p = kv + (size_t)row * 512 + lane * 8;
    float4 u0 = *(float4*)p;
    float4 u1 = *(float4*)(p + 4);
    float v[8] = {u0.x, u0.y, u0.z, u0.w, u1.x, u1.y, u1.z, u1.w};
    float s = 0.f, s2 = 0.f;
#pragma unroll
    for (int i = 0; i < 8; ++i) { s += v[i]; s2 += v[i] * v[i]; }
#pragma unroll
    for (int off = 32; off >= 1; off >>= 1) {
        s += __shfl_xor(s, off, 64);
        s2 += __shfl_xor(s2, off, 64);
    }
    float m = s * (1.f / 512.f);
    float var = s2 * (1.f / 512.f) - m * m;
    float rs = rsqrtf(var + 1e-5f);
    const float* gp = g + lane * 8;
    const float* bp = be + lane * 8;
#pragma unroll
    for (int i = 0; i < 8; ++i) v[i] = (v[i] - m) * rs * gp[i] + bp[i];
    *(float4*)p = make_float4(v[0], v[1], v[2], v[3]);
    *(float4*)(p + 4) = make_float4(v[4], v[5], v[6], v[7]);
}

// ---------------------------------------------- bias-fold: out[j] = vin@B[:,j] + badd[j]
__global__ __launch_bounds__(256) void k_bvec(
    const float* __restrict__ vin, const float* __restrict__ B, int ldb,
    const float* __restrict__ badd, float* __restrict__ out, int Nj)
{
    int j = blockIdx.x * 256 + threadIdx.x;
    if (j >= Nj) return;
    float s = 0.f;
    for (int e = 0; e < 512; ++e) s += vin[e] * B[(size_t)e * ldb + j];
    out[j] = s + badd[j];
}

// ---------------------------------------------- f32 -> bf16 convert
__global__ __launch_bounds__(256) void k_convert(
    const float* __restrict__ src, u16* __restrict__ dst, int n)
{
    int g = blockIdx.x * 256 + threadIdx.x;
    int T = gridDim.x * 256;
    for (int i = g; i < n; i += T) dst[i] = f2bf(src[i]);
}

// ---------------------------------------------- W_out [512][1000] -> WT [1000][512] bf16
__global__ __launch_bounds__(256) void k_transpose_wout(
    const float* __restrict__ W, u16* __restrict__ WT)
{
    int j = blockIdx.x * 256 + threadIdx.x;
    if (j >= 1000) return;
    for (int k = 0; k < 512; ++k) WT[(size_t)j * 512 + k] = f2bf(W[(size_t)k * 1000 + j]);
}

// ---------------------------------------------- V [b,n,h,d] -> VT [b,h,d,n] bf16
__global__ __launch_bounds__(256) void k_transpose_v(
    const u16* __restrict__ V, u16* __restrict__ VT)
{
    int bh = blockIdx.x;
    int b = bh >> 3, h = bh & 7;
    int tid = threadIdx.x;
    const u16* src = V + (size_t)b * 1024 * 512 + h * 64;
    u16* dst = VT + (size_t)bh * 64 * 1024;
    int n0 = tid * 4;
    for (int d = 0; d < 64; ++d) {
        u16 a0 = src[(size_t)(n0 + 0) * 512 + d];
        u16 a1 = src[(size_t)(n0 + 1) * 512 + d];
        u16 a2 = src[(size_t)(n0 + 2) * 512 + d];
        u16 a3 = src[(size_t)(n0 + 3) * 512 + d];
        uint2 w = make_uint2((unsigned)a0 | ((unsigned)a1 << 16),
                             (unsigned)a2 | ((unsigned)a3 << 16));
        *(uint2*)&dst[(size_t)d * 1024 + n0] = w;
    }
}

// ================================================================ persistent loop
#define NBLK 1024

struct LoopP {
    const u16* Wqq; const float* bqq;
    const u16* K;   const u16* VT;
    const u16* Wfull; const float* bcomb;
    const u16* W1; const float* b1;
    const u16* W2; const float* b2;
    const u16* WoutT; const float* bout;
    const int* idxA; const int* idxO;
    const float* r_a; const float* r_o;
    float* aA0; float* aA1; float* bA0; float* bA1;
    float* aO0; float* aO1; float* bO0; float* bO1;
    float* act0; float* act1;
    float* pvp; float* mz;                 // [4][256][64] ; [4][256] float2 (m,z)
    float* attn_f; float* actR;            // [32][512] ; [32][2048]
    float* h_pre; float* hpm; float* t1;
    float* out;
    const float* gsyn; const float* besyn; const float* gpm; const float* bepm;
    unsigned* bar;
};

union Smem {
    struct { float sA[512]; float qh[64]; float sc[256]; float red[512]; } at; // 5376 B
    struct { float mzs[64]; float arow[512]; } b2;                             // 2304 B
    struct { float As[2560]; float red[512]; float orow[128]; } ck;            // 12800 B
    struct { float As[2048]; float red[512]; float orow[64]; } ek;             // 10496 B
    struct { float red[16]; } gl;
    struct { float sO[512]; float red[8]; } pr;                                // 2080 B
};

// Tree grid barrier (r6-proven): 16 arrival counters -> 1 root -> 32 gen lines.
__device__ __forceinline__ void gridbar(unsigned* bar)
{
    __syncthreads();
    if (threadIdx.x == 0) {
        int blk = blockIdx.x;
        unsigned* cnt1 = bar + ((blk >> 6) << 5);          // 16 lines
        unsigned* cnt2 = bar + (16 << 5);
        unsigned* genp = bar + ((17 + (blk & 31)) << 5);   // 32 lines
        unsigned g = __hip_atomic_load(genp, __ATOMIC_RELAXED, __HIP_MEMORY_SCOPE_AGENT);
        asm volatile("s_waitcnt vmcnt(0)" ::: "memory");   // g settled before arrival
        unsigned a = __hip_atomic_fetch_add(cnt1, 1u, __ATOMIC_RELAXED, __HIP_MEMORY_SCOPE_AGENT);
        if (a == 63u) {
            __hip_atomic_store(cnt1, 0u, __ATOMIC_RELAXED, __HIP_MEMORY_SCOPE_AGENT);
            asm volatile("s_waitcnt vmcnt(0)" ::: "memory");  // reset lands first
            unsigned a2 = __hip_atomic_fetch_add(cnt2, 1u, __ATOMIC_RELAXED, __HIP_MEMORY_SCOPE_AGENT);
            if (a2 == 15u) {
                __hip_atomic_store(cnt2, 0u, __ATOMIC_RELAXED, __HIP_MEMORY_SCOPE_AGENT);
                asm volatile("s_waitcnt vmcnt(0)" ::: "memory");
#pragma unroll
                for (int r = 0; r < 32; ++r)
                    __hip_atomic_store(bar + ((17 + r) << 5), g + 1u,
                                       __ATOMIC_RELAXED, __HIP_MEMORY_SCOPE_AGENT);
            }
        }
        unsigned cur;
        do {
            cur = __hip_atomic_load(genp, __ATOMIC_RELAXED, __HIP_MEMORY_SCOPE_AGENT);
            if (cur != g) break;
            __builtin_amdgcn_s_sleep(2);
        } while (true);
        asm volatile("" ::: "memory");
    }
    __syncthreads();
}

__device__ __forceinline__ void red2(float& a, float& b, float* red, int tid)
{
#pragma unroll
    for (int off = 32; off >= 1; off >>= 1) {
        a += __shfl_xor(a, off, 64);
        b += __shfl_xor(b, off, 64);
    }
    __syncthreads();
    if ((tid & 63) == 0) { red[(tid >> 6) * 2] = a; red[(tid >> 6) * 2 + 1] = b; }
    __syncthreads();
    float sa = 0.f, sb = 0.f;
#pragma unroll
    for (int w = 0; w < 8; ++w) { sa += red[2 * w]; sb += red[2 * w + 1]; }
    a = sa; b = sb;
}

__global__ __launch_bounds__(512, 8) void k_loop(LoopP P)
{
    __shared__ Smem s;
    const int tid = threadIdx.x;
    const int blk = blockIdx.x;
    const int lane = tid & 63;
    const int wav = tid >> 6;

    for (int t = 0; t < 50; ++t) {
        const float* actprev = (t & 1) ? P.act1 : P.act0;
        float*       actnext = (t & 1) ? P.act0 : P.act1;
        const float* aAp = (t & 1) ? P.aA1 : P.aA0;  float* aAc = (t & 1) ? P.aA0 : P.aA1;
        const float* bAp = (t & 1) ? P.bA1 : P.bA0;  float* bAc = (t & 1) ? P.bA0 : P.bA1;
        const float* aOp = (t & 1) ? P.aO1 : P.aO0;  float* aOc = (t & 1) ? P.aO0 : P.aO1;
        const float* bOp = (t & 1) ? P.bO1 : P.bO0;  float* bOc = (t & 1) ? P.bO0 : P.bO1;

        __syncthreads();   // protect LDS union against previous phase readers

        // ============ phase B : 4-way-split attention (all 1024 blocks) ======
        {
            int bh = blk >> 2, p = blk & 3;      // 256 (b,h) groups x 4 n-parts
            int b = bh >> 3, h = bh & 7;
            // p==0 blocks also precompute actR[b] slice (relu(act+b2), once/step)
            if (p == 0 && tid < 64) {
                int i4 = (h * 64 + tid) * 4;
                fv4 v;
                cload(v, &actprev[b * 2048 + i4]);
                cwait1(v);
                if (t > 0) {
                    float4 b4 = *(const float4*)&P.b2[i4];
                    v.x = fmaxf(0.f, v.x + b4.x);
                    v.y = fmaxf(0.f, v.y + b4.y);
                    v.z = fmaxf(0.f, v.z + b4.z);
                    v.w = fmaxf(0.f, v.w + b4.w);
                }
                cstore4(&P.actR[b * 2048 + i4], v);
            }
            {   // syncA (32 dup writers per (b,j) -- identical values, benign)
                int j = tid;
                int ia = P.idxA[j];
                float v = aload(&actprev[b * 2048 + ia]);
                if (t > 0) v = fmaxf(0.f, v + P.b2[ia]);
                float r = P.r_a[j];
                float a = r * aAp[b * 512 + j] + v * v;
                float bb = r * bAp[b * 512 + j] + 1.f;
                aAc[b * 512 + j] = a; bAc[b * 512 + j] = bb;
                s.at.sA[j] = a * rsqrtf(bb);
            }
            __syncthreads();
            {   // qh = sA @ Wqq slice  (8-way K split)
                int d = tid & 63, kg = tid >> 6;
                const u16* wp = P.Wqq + (size_t)(kg * 64) * 512 + h * 64 + d;
                const float* ap = s.at.sA + kg * 64;
                float pq = 0.f;
#pragma unroll 16
                for (int k = 0; k < 64; ++k) pq += ap[k] * bf2f(wp[(size_t)k * 512]);
                s.at.red[tid] = pq;
            }
            __syncthreads();
            if (tid < 64) {
                float q = P.bqq[h * 64 + tid];
#pragma unroll
                for (int g2 = 0; g2 < 8; ++g2) q += s.at.red[g2 * 64 + tid];
                s.at.qh[tid] = q;
            }
            __syncthreads();
            // scores for this part's 256 rows (1 row per thread, tid<256)
            if (tid < 256) {
                const u16* Kbh = P.K + (size_t)b * 1024 * 512 + h * 64;
                const uv4* kp = (const uv4*)(Kbh + (size_t)(p * 256 + tid) * 512);
                uv4 u[8];
#pragma unroll
                for (int i = 0; i < 8; ++i) u[i] = __builtin_nontemporal_load(kp + i);
                float dot = 0.f;
#pragma unroll
                for (int i = 0; i < 8; ++i) {
                    float4 q0 = *(float4*)&s.at.qh[i * 8];
                    float4 q1 = *(float4*)&s.at.qh[i * 8 + 4];
                    dot += q0.x * bflo(u[i].x) + q0.y * bfhi(u[i].x)
                         + q0.z * bflo(u[i].y) + q0.w * bfhi(u[i].y)
                         + q1.x * bflo(u[i].z) + q1.y * bfhi(u[i].z)
                         + q1.z * bflo(u[i].w) + q1.w * bfhi(u[i].w);
                }
                s.at.sc[tid] = dot * 0.125f;
            }
            __syncthreads();
            // local max over 256
            float mv = (tid < 256) ? s.at.sc[tid] : -1e30f;
#pragma unroll
            for (int off = 32; off >= 1; off >>= 1) mv = fmaxf(mv, __shfl_xor(mv, off, 64));
            if (lane == 0) s.at.red[wav] = mv;
            __syncthreads();
            float mloc = s.at.red[0];
#pragma unroll
            for (int w = 1; w < 8; ++w) mloc = fmaxf(mloc, s.at.red[w]);
            // exp + local sum
            float ev = 0.f;
            if (tid < 256) {
                ev = __expf(s.at.sc[tid] - mloc);
                s.at.sc[tid] = ev;
            }
            float zv = ev;
#pragma unroll
            for (int off = 32; off >= 1; off >>= 1) zv += __shfl_xor(zv, off, 64);
            __syncthreads();
            if (lane == 0) s.at.red[wav] = zv;
            __syncthreads();
            float Zloc = 0.f;
#pragma unroll
            for (int w = 0; w < 8; ++w) Zloc += s.at.red[w];
            __syncthreads();   // red reads done before PV rewrites red
            // PV over this part's 256 rows: 8 groups x 32 rows
            {
                int d = tid & 63, ng = tid >> 6;
                const uv4* vp = (const uv4*)(P.VT
                    + ((size_t)bh * 64 + d) * 1024 + p * 256 + ng * 32);
                float acc = 0.f;
#pragma unroll
                for (int i = 0; i < 4; ++i) {
                    uv4 u = __builtin_nontemporal_load(vp + i);
                    const float* so = s.at.sc + ng * 32 + i * 8;
                    acc += so[0] * bflo(u.x) + so[1] * bfhi(u.x)
                         + so[2] * bflo(u.y) + so[3] * bfhi(u.y)
                         + so[4] * bflo(u.z) + so[5] * bfhi(u.z)
                         + so[6] * bflo(u.w) + so[7] * bfhi(u.w);
                }
                s.at.red[tid] = acc;
            }
            __syncthreads();
            if (tid < 64) {
                float a = 0.f;
#pragma unroll
                for (int g2 = 0; g2 < 8; ++g2) a += s.at.red[g2 * 64 + tid];
                s.at.qh[tid] = a;                  // reuse qh as pv staging
            }
            __syncthreads();
            if (tid < 16) {                        // 16B coherent pv write
                fv4 v = *(fv4*)&s.at.qh[tid * 4];
                cstore4(&P.pvp[((size_t)p * 256 + bh) * 64 + tid * 4], v);
            }
            if (tid == 0) {                        // 8B coherent (m,z) write
                fv2 v; v.x = mloc; v.y = Zloc;
                cstore2(&P.mz[(p * 256 + bh) * 2], v);
            }
        }
        gridbar(P.bar);

        // ============ phase B2 : combine softmax partials -> attn_f (32 blocks)
        if (blk < 32) {
            int b = blk;
            if (tid < 32) {        // mz -> LDS: tid = p*8 + h
                int p = tid >> 3, h = tid & 7;
                fv2 v;
                cload2(v, &P.mz[(p * 256 + b * 8 + h) * 2]);
                cwaitf2(v);
                s.b2.mzs[tid * 2] = v.x;
                s.b2.mzs[tid * 2 + 1] = v.y;
            }
            __syncthreads();
            int h = tid >> 6, d = tid & 63;
            int rh = b * 8 + h;
            float m0 = s.b2.mzs[(0 * 8 + h) * 2], z0 = s.b2.mzs[(0 * 8 + h) * 2 + 1];
            float m1 = s.b2.mzs[(1 * 8 + h) * 2], z1 = s.b2.mzs[(1 * 8 + h) * 2 + 1];
            float m2 = s.b2.mzs[(2 * 8 + h) * 2], z2 = s.b2.mzs[(2 * 8 + h) * 2 + 1];
            float m3 = s.b2.mzs[(3 * 8 + h) * 2], z3 = s.b2.mzs[(3 * 8 + h) * 2 + 1];
            float M = fmaxf(fmaxf(m0, m1), fmaxf(m2, m3));
            float e0 = __expf(m0 - M), e1 = __expf(m1 - M);
            float e2 = __expf(m2 - M), e3 = __expf(m3 - M);
            float Zinv = 1.f / (z0 * e0 + z1 * e1 + z2 * e2 + z3 * e3);
            float acc = aload(&P.pvp[((size_t)0 * 256 + rh) * 64 + d]) * e0
                      + aload(&P.pvp[((size_t)1 * 256 + rh) * 64 + d]) * e1
                      + aload(&P.pvp[((size_t)2 * 256 + rh) * 64 + d]) * e2
                      + aload(&P.pvp[((size_t)3 * 256 + rh) * 64 + d]) * e3;
            s.b2.arow[tid] = acc * Zinv;
            __syncthreads();
            if (tid < 128) {
                fv4 v = *(fv4*)&s.b2.arow[tid * 4];
                cstore4(&P.attn_f[b * 512 + tid * 4], v);
            }
        }
        gridbar(P.bar);

        // ============ phase C : h_pre[b] = [attn_f[b]|actR[b]] @ Wfull =======
        // 1024 blocks = 32 b-rows x 32 j-chunks(128 j); full-K per block.
        {
            int b = blk >> 5, jc = blk & 31;
            int j0 = jc * 128;
            // stage A row (2560 f32 = 640 f4) into LDS
            if (tid < 128) {
                fv4 v; cload(v, &P.attn_f[b * 512 + tid * 4]); cwait1(v);
                *(fv4*)&s.ck.As[tid * 4] = v;
            } else {
                fv4 v; cload(v, &P.actR[b * 2048 + (tid - 128) * 4]); cwait1(v);
                *(fv4*)&s.ck.As[512 + (tid - 128) * 4] = v;
            }
            if (tid < 128) {
                fv4 v; cload(v, &P.actR[b * 2048 + (384 + tid) * 4]); cwait1(v);
                *(fv4*)&s.ck.As[512 + (384 + tid) * 4] = v;
            }
            __syncthreads();
            int j = j0 + (tid & 127);
            int kq = tid >> 7;                    // 4 quarters x 640 k
            const u16* wp = P.Wfull + (size_t)(kq * 640) * 4096 + j;
            const float* ap = s.ck.As + kq * 640;
            float acc = 0.f;
#pragma unroll 32
            for (int k = 0; k < 640; ++k) acc += ap[k] * bf2f(wp[(size_t)k * 4096]);
            s.ck.red[kq * 128 + (tid & 127)] = acc;
            __syncthreads();
            if (tid < 128) {
                s.ck.orow[tid] = s.ck.red[tid] + s.ck.red[128 + tid]
                               + s.ck.red[256 + tid] + s.ck.red[384 + tid];
            }
            __syncthreads();
            if (tid < 32) {
                fv4 v = *(fv4*)&s.ck.orow[tid * 4];
                cstore4(&P.h_pre[(size_t)b * 4096 + j0 + tid * 4], v);
            }
        }
        gridbar(P.bar);

        // ============ phase D : GLU + double LayerNorm (32 blocks, f4) =====
        if (blk < 32) {
            const float* hr = P.h_pre + (size_t)blk * 4096;
            int i4 = tid * 4;
            fv4 av, gv;
            cload(av, hr + i4);
            cload(gv, hr + 2048 + i4);
            cwait2(av, gv);
            float4 bc1 = *(const float4*)&P.bcomb[i4];
            float4 bc2 = *(const float4*)&P.bcomb[2048 + i4];
            fv4 z;
            z.x = (av.x + bc1.x) / (1.f + __expf(-(gv.x + bc2.x)));
            z.y = (av.y + bc1.y) / (1.f + __expf(-(gv.y + bc2.y)));
            z.z = (av.z + bc1.z) / (1.f + __expf(-(gv.z + bc2.z)));
            z.w = (av.w + bc1.w) / (1.f + __expf(-(gv.w + bc2.w)));
            float sa = z.x + z.y + z.z + z.w;
            float sb = z.x * z.x + z.y * z.y + z.z * z.z + z.w * z.w;
            red2(sa, sb, s.gl.red, tid);
            float m1 = sa * (1.f / 2048.f);
            float v1 = sb * (1.f / 2048.f) - m1 * m1;
            float rs1 = rsqrtf(v1 + 1e-5f);
            float4 gs = *(const float4*)&P.gsyn[i4];
            float4 bs = *(const float4*)&P.besyn[i4];
            z.x = (z.x - m1) * rs1 * gs.x + bs.x;
            z.y = (z.y - m1) * rs1 * gs.y + bs.y;
            z.z = (z.z - m1) * rs1 * gs.z + bs.z;
            z.w = (z.w - m1) * rs1 * gs.w + bs.w;
            float ta = z.x + z.y + z.z + z.w;
            float tb = z.x * z.x + z.y * z.y + z.z * z.z + z.w * z.w;
            red2(ta, tb, s.gl.red, tid);
            float m2 = ta * (1.f / 2048.f);
            float v2 = tb * (1.f / 2048.f) - m2 * m2;
            float rs2 = rsqrtf(v2 + 1e-5f);
            float4 gp = *(const float4*)&P.gpm[i4];
            float4 bp = *(const float4*)&P.bepm[i4];
            fv4 o;
            o.x = (z.x - m2) * rs2 * gp.x + bp.x;
            o.y = (z.y - m2) * rs2 * gp.y + bp.y;
            o.z = (z.z - m2) * rs2 * gp.z + bp.z;
            o.w = (z.w - m2) * rs2 * gp.w + bp.w;
            cstore4(&P.hpm[(size_t)blk * 2048 + i4], o);
        }
        gridbar(P.bar);

        // ============ phase E : t1[b] = hpm[b] @ W1 (32 b x 32 jc of 64 j) ==
        {
            int b = blk >> 5, jc = blk & 31;
            int j0 = jc * 64;
            {   // stage hpm row (2048 f32 = 512 f4)
                fv4 v; cload(v, &P.hpm[(size_t)b * 2048 + tid * 4]); cwait1(v);
                *(fv4*)&s.ek.As[tid * 4] = v;
            }
            __syncthreads();
            int j = j0 + (tid & 63), kq = tid >> 6;   // 8 quarters x 256 k
            const u16* wp = P.W1 + (size_t)(kq * 256) * 2048 + j;
            const float* ap = s.ek.As + kq * 256;
            float acc = 0.f;
#pragma unroll 32
            for (int k = 0; k < 256; ++k) acc += ap[k] * bf2f(wp[(size_t)k * 2048]);
            s.ek.red[kq * 64 + (tid & 63)] = acc;
            __syncthreads();
            if (tid < 64) {
                float v = 0.f;
#pragma unroll
                for (int q = 0; q < 8; ++q) v += s.ek.red[q * 64 + tid];
                s.ek.orow[tid] = v;
            }
            __syncthreads();
            if (tid < 16) {
                fv4 v = *(fv4*)&s.ek.orow[tid * 4];
                cstore4(&P.t1[(size_t)b * 2048 + j0 + tid * 4], v);
            }
        }
        gridbar(P.bar);

        // ============ phase F : actnext[b] = relu(t1[b]+b1) @ W2 ===========
        {
            int b = blk >> 5, jc = blk & 31;
            int j0 = jc * 64;
            {   // stage relu(t1+b1) row
                fv4 v; cload(v, &P.t1[(size_t)b * 2048 + tid * 4]); cwait1(v);
                float4 b4 = *(const float4*)&P.b1[tid * 4];
                v.x = fmaxf(0.f, v.x + b4.x);
                v.y = fmaxf(0.f, v.y + b4.y);
                v.z = fmaxf(0.f, v.z + b4.z);
                v.w = fmaxf(0.f, v.w + b4.w);
                *(fv4*)&s.ek.As[tid * 4] = v;
            }
            __syncthreads();
            int j = j0 + (tid & 63), kq = tid >> 6;
            const u16* wp = P.W2 + (size_t)(kq * 256) * 2048 + j;
            const float* ap = s.ek.As + kq * 256;
            float acc = 0.f;
#pragma unroll 32
            for (int k = 0; k < 256; ++k) acc += ap[k] * bf2f(wp[(size_t)k * 2048]);
            s.ek.red[kq * 64 + (tid & 63)] = acc;
            __syncthreads();
            if (tid < 64) {
                float v = 0.f;
#pragma unroll
                for (int q = 0; q < 8; ++q) v += s.ek.red[q * 64 + tid];
                s.ek.orow[tid] = v;
            }
            __syncthreads();
            if (tid < 16) {
                fv4 v = *(fv4*)&s.ek.orow[tid * 4];
                cstore4(&actnext[(size_t)b * 2048 + j0 + tid * 4], v);
            }
        }
        gridbar(P.bar);

        // ============ phase HI : syncO + pred (transposed Wout) + entropy ==
        if (blk < 32) {
            int b = blk;
            {   // syncO (block-exclusive aO state)
                int j2 = tid;
                int io = P.idxO[j2];
                float v = fmaxf(0.f, aload(&actnext[b * 2048 + io]) + P.b2[io]);
                float r = P.r_o[j2];
                float a = r * aOp[b * 512 + j2] + v * v;
                float bb = r * bOp[b * 512 + j2] + 1.f;
                aOc[b * 512 + j2] = a; bOc[b * 512 + j2] = bb;
                float sy = a * rsqrtf(bb);
                s.pr.sO[j2] = sy;
                if (t == 49) P.out[1603200 + b * 512 + j2] = sy;
            }
            __syncthreads();
            bool has1 = tid < 488;       // tid+512 < 1000
            float p0, p1 = -1e30f;
            {
                const uint4* wp = (const uint4*)(P.WoutT + (size_t)tid * 512);
                float acc = 0.f;
#pragma unroll 16
                for (int i = 0; i < 64; ++i) {
                    uint4 u = wp[i];
                    const float* so = s.pr.sO + i * 8;
                    acc += so[0] * bflo(u.x) + so[1] * bfhi(u.x)
                         + so[2] * bflo(u.y) + so[3] * bfhi(u.y)
                         + so[4] * bflo(u.z) + so[5] * bfhi(u.z)
                         + so[6] * bflo(u.w) + so[7] * bfhi(u.w);
                }
                p0 = acc + P.bout[tid];
            }
            if (has1) {
                const uint4* wp = (const uint4*)(P.WoutT + (size_t)(tid + 512) * 512);
                float acc = 0.f;
#pragma unroll 16
                for (int i = 0; i < 64; ++i) {
                    uint4 u = wp[i];
                    const float* so = s.pr.sO + i * 8;
                    acc += so[0] * bflo(u.x) + so[1] * bfhi(u.x)
                         + so[2] * bflo(u.y) + so[3] * bfhi(u.y)
                         + so[4] * bflo(u.z) + so[5] * bfhi(u.z)
                         + so[6] * bflo(u.w) + so[7] * bfhi(u.w);
                }
                p1 = acc + P.bout[tid + 512];
            }
            // entropy over {p0, p1}
            float mx = fmaxf(p0, p1);
#pragma unroll
            for (int off = 32; off >= 1; off >>= 1) mx = fmaxf(mx, __shfl_xor(mx, off, 64));
            __syncthreads();
            if (lane == 0) s.pr.red[wav] = mx;
            __syncthreads();
            mx = s.pr.red[0];
#pragma unroll
            for (int w = 1; w < 8; ++w) mx = fmaxf(mx, s.pr.red[w]);
            float zs = __expf(p0 - mx) + (has1 ? __expf(p1 - mx) : 0.f);
#pragma unroll
            for (int off = 32; off >= 1; off >>= 1) zs += __shfl_xor(zs, off, 64);
            __syncthreads();
            if (lane == 0) s.pr.red[wav] = zs;
            __syncthreads();
            float Z = 0.f;
#pragma unroll
            for (int w = 0; w < 8; ++w) Z += s.pr.red[w];
            float logZ = __logf(Z);
            float lp0 = p0 - mx - logZ;
            float se = __expf(lp0) * lp0;
            if (has1) { float lp1 = p1 - mx - logZ; se += __expf(lp1) * lp1; }
#pragma unroll
            for (int off = 32; off >= 1; off >>= 1) se += __shfl_xor(se, off, 64);
            __syncthreads();
            if (lane == 0) s.pr.red[wav] = se;
            __syncthreads();
            float S = 0.f;
#pragma unroll
            for (int w = 0; w < 8; ++w) S += s.pr.red[w];
            float ne = -S / logf(1000.0f);
            P.out[(size_t)b * 50000 + (size_t)tid * 50 + t] = p0;
            if (has1) P.out[(size_t)b * 50000 + (size_t)(tid + 512) * 50 + t] = p1;
            if (tid == 0) {
                P.out[1600000 + b * 100 + t] = ne;
                P.out[1600000 + b * 100 + 50 + t] = 1.f - ne;
            }
        }
        // no grid barrier before next step: B(t+1) reads actprev(=actnext(t),
        // F, 1 barrier back) and block-own aA state; HI's outputs (aO, out)
        // are block-exclusive. actR/attn_f/pvp/mz/h_pre/hpm/t1 single-buffered:
        // each is rewritten >=1 barrier after its last reader of step t.
    }
}

// ================================================================ host launcher
extern "C" void kernel_launch(void* const* d_in, const int* in_sizes, int n_in,
                              void* d_out, int out_size, void* d_ws, size_t ws_size,
                              hipStream_t stream)
{
    const float* x      = (const float*)d_in[0];
    const float* W_kv   = (const float*)d_in[1];
    const float* b_kv   = (const float*)d_in[2];
    const float* g_kv   = (const float*)d_in[3];
    const float* be_kv  = (const float*)d_in[4];
    const float* W_q    = (const float*)d_in[5];
    const float* b_q    = (const float*)d_in[6];
    const float* W_in   = (const float*)d_in[7];
    const float* b_in   = (const float*)d_in[8];
    const float* W_ao   = (const float*)d_in[9];
    const float* b_ao   = (const float*)d_in[10];
    const float* W_syn  = (const float*)d_in[11];
    const float* b_syn  = (const float*)d_in[12];
    const float* g_syn  = (const float*)d_in[13];
    const float* be_syn = (const float*)d_in[14];
    const float* g_pm   = (const float*)d_in[15];
    const float* be_pm  = (const float*)d_in[16];
    const float* W1     = (const float*)d_in[17];
    const float* b1     = (const float*)d_in[18];
    const float* W2     = (const float*)d_in[19];
    const float* b2     = (const float*)d_in[20];
    const float* start_state  = (const float*)d_in[21];
    const float* decay_action = (const float*)d_in[22];
    const float* decay_out    = (const float*)d_in[23];
    const float* W_out  = (const float*)d_in[24];
    const float* b_out  = (const float*)d_in[25];
    const int* idx_action = (const int*)d_in[26];
    const int* idx_out    = (const int*)d_in[27];
    float* out = (float*)d_out;

    char* ws = (char*)d_ws;
    size_t off = 0;
    auto take = [&](size_t bytes) -> char* {
        char* p = ws + off;
        off += (bytes + 255) & ~(size_t)255;
        return p;
    };

    // region0: kv (fp32, precompute-only), later aliased by loop weights
    char* region0 = take(67108864);                 // 32768*512*4
    float* kv = (float*)region0;
    u16* W_full = (u16*)region0;                    // 2560 x 4096 bf16 = 20,971,520
    u16* W1b    = (u16*)(region0 + 20971520);       // 8,388,608
    u16* W2b    = (u16*)(region0 + 29360128);       // 8,388,608
    u16* WoutT  = (u16*)(region0 + 37748736);       // 1000 x 512 bf16 = 1,024,000
    u16* Wqqb   = (u16*)(region0 + 38772736);       // 524,288

    u16* K_bf = (u16*)take(33554432);
    u16* V_bf = (u16*)take(33554432);
    u16* V_T  = (u16*)take(33554432);
    float* b_qq   = (float*)take(2048);
    float* b_comb = (float*)take(16384);
    float* r_a = (float*)take(2048);
    float* r_o = (float*)take(2048);
    float* aA0 = (float*)take(65536);
    float* aA1 = (float*)take(65536);
    float* bA0 = (float*)take(65536);
    float* bA1 = (float*)take(65536);
    float* aO0 = (float*)take(65536);
    float* aO1 = (float*)take(65536);
    float* bO0 = (float*)take(65536);
    float* bO1 = (float*)take(65536);
    float* act0v = (float*)take(262144);
    float* act1v = (float*)take(262144);
    float* h_pre = (float*)take(524288);
    float* hpm   = (float*)take(262144);
    float* t1_pre = (float*)take(262144);
    float* pvp = (float*)take(262144);       // [4][256][64]
    float* mzB = (float*)take(8192);         // [4][256] float2
    float* attn_f = (float*)take(65536);     // [32][512]
    float* actR   = (float*)take(262144);    // [32][2048]
    unsigned* bar = (unsigned*)take(8192);
    (void)ws_size; (void)in_sizes; (void)n_in; (void)out_size;

    // ---------------- precompute ----------------
    k_init<<<256, 256, 0, stream>>>(start_state, decay_action, decay_out,
                                    act0v, aA0, bA0, aO0, bO0, r_a, r_o, bar);
    k_gemm_xT<<<dim3(4, 512), 256, 0, stream>>>(x, W_kv, b_kv, kv);
    k_ln_kv<<<8192, 256, 0, stream>>>(kv, g_kv, be_kv);
    k_gemm_AB<<<dim3(4, 512), 256, 0, stream>>>(kv, 512, W_in + 512, 1536, b_in + 512, K_bf, 512);
    k_gemm_AB<<<dim3(4, 512), 256, 0, stream>>>(kv, 512, W_in + 1024, 1536, b_in + 1024, V_bf, 512);
    k_transpose_v<<<256, 256, 0, stream>>>(V_bf, V_T);
    // kv now dead -> region0 reused for loop weights
    k_gemm_AB<<<dim3(4, 8), 256, 0, stream>>>(W_q, 512, W_in, 1536, nullptr, Wqqb, 512);
    k_gemm_AB<<<dim3(32, 8), 256, 0, stream>>>(W_ao, 512, W_syn, 4096, nullptr, W_full, 4096);
    k_bvec<<<2, 256, 0, stream>>>(b_q, W_in, 1536, b_in, b_qq, 512);
    k_bvec<<<16, 256, 0, stream>>>(b_ao, W_syn, 4096, b_syn, b_comb, 4096);
    k_convert<<<2048, 256, 0, stream>>>(W_syn + (size_t)512 * 4096, W_full + (size_t)512 * 4096, 2048 * 4096);
    k_convert<<<2048, 256, 0, stream>>>(W1, W1b, 2048 * 2048);
    k_convert<<<2048, 256, 0, stream>>>(W2, W2b, 2048 * 2048);
    k_transpose_wout<<<4, 256, 0, stream>>>(W_out, WoutT);

    // ---------------- recurrent loop: persistent kernel, plain launch ----------
    // 1024 blocks x 512 threads = exactly 4 blocks/CU (32 waves = HW max).
    LoopP p;
    p.Wqq = Wqqb; p.bqq = b_qq;
    p.K = K_bf;   p.VT = V_T;
    p.Wfull = W_full; p.bcomb = b_comb;
    p.W1 = W1b; p.b1 = b1;
    p.W2 = W2b; p.b2 = b2;
    p.WoutT = WoutT; p.bout = b_out;
    p.idxA = idx_action; p.idxO = idx_out;
    p.r_a = r_a; p.r_o = r_o;
    p.aA0 = aA0; p.aA1 = aA1; p.bA0 = bA0; p.bA1 = bA1;
    p.aO0 = aO0; p.aO1 = aO1; p.bO0 = bO0; p.bO1 = bO1;
    p.act0 = act0v; p.act1 = act1v;
    p.pvp = pvp; p.mz = mzB;
    p.attn_f = attn_f; p.actR = actR;
    p.h_pre = h_pre; p.hpm = hpm; p.t1 = t1_pre;
    p.out = out;
    p.gsyn = g_syn; p.besyn = be_syn; p.gpm = g_pm; p.bepm = be_pm;
    p.bar = bar;

    k_loop<<<dim3(NBLK), dim3(512), 0, stream>>>(p);
}

// Round 9
// 10323.943 us; speedup vs baseline: 1.8942x; 1.8942x over previous
//
#include <hip/hip_runtime.h>

// ContinuousThoughtMachineReLU  (B=32, C=512, N=1024, E=512, D=2048, H=8, hd=64,
//                                T=50, O=1000, NA=512, NO=512)
//
// Round 9: r8 regressed 2x -- b-row full-K read weights 32x redundantly.
// Hybrid: r7's proven splitK C/E/F (atomicAdd, weights read once/step)
// + r8's proven B2 pre-combine (attn_f) and actR precompute, which collapse
// C's per-tile 4-way pvp gather into two plain wide-load streams.
// Model (validated r6/r7): step time = coherent bytes / 1.28 TB/s.
// Bytes ~188 -> ~155 MB/step.

typedef unsigned short u16;
typedef unsigned int uv4 __attribute__((ext_vector_type(4)));   // nt-loadable
typedef float fv4 __attribute__((ext_vector_type(4)));
typedef float fv2 __attribute__((ext_vector_type(2)));

__device__ __forceinline__ float bf2f(u16 u) {
    return __uint_as_float(((unsigned int)u) << 16);
}
__device__ __forceinline__ float bflo(unsigned int u) { return __uint_as_float(u << 16); }
__device__ __forceinline__ float bfhi(unsigned int u) { return __uint_as_float(u & 0xffff0000u); }
__device__ __forceinline__ u16 f2bf(float f) {
    unsigned int u = __float_as_uint(f);
    unsigned int r = u + 0x7fffu + ((u >> 16) & 1u);
    return (u16)(r >> 16);
}

// ---- coherence-point (L2-bypassing) wide accessors: sc0 sc1 ----
__device__ __forceinline__ void cload(fv4& r, const void* p) {
    asm volatile("global_load_dwordx4 %0, %1, off sc0 sc1" : "=v"(r) : "v"(p));
}
__device__ __forceinline__ void cload2(fv2& r, const void* p) {
    asm volatile("global_load_dwordx2 %0, %1, off sc0 sc1" : "=v"(r) : "v"(p));
}
__device__ __forceinline__ void cstore4(void* p, fv4 v) {
    asm volatile("global_store_dwordx4 %0, %1, off sc0 sc1" :: "v"(p), "v"(v) : "memory");
}
__device__ __forceinline__ void cstore2(void* p, fv2 v) {
    asm volatile("global_store_dwordx2 %0, %1, off sc0 sc1" :: "v"(p), "v"(v) : "memory");
}
__device__ __forceinline__ void cwait1(fv4& a) {
    asm volatile("s_waitcnt vmcnt(0)" : "+v"(a) :: "memory");
    __builtin_amdgcn_sched_barrier(0);
}
__device__ __forceinline__ void cwait2(fv4& a, fv4& b) {
    asm volatile("s_waitcnt vmcnt(0)" : "+v"(a), "+v"(b) :: "memory");
    __builtin_amdgcn_sched_barrier(0);
}
__device__ __forceinline__ void cwaitf2(fv2& a) {
    asm volatile("s_waitcnt vmcnt(0)" : "+v"(a) :: "memory");
    __builtin_amdgcn_sched_barrier(0);
}

// agent-scope scalar accessors (for gathers only)
__device__ __forceinline__ float aload(const float* p) {
    return __hip_atomic_load((const float*)p, __ATOMIC_RELAXED, __HIP_MEMORY_SCOPE_AGENT);
}

// ---------------------------------------------------------------- init
__global__ __launch_bounds__(256) void k_init(
    const float* __restrict__ start_state, const float* __restrict__ dec_a,
    const float* __restrict__ dec_o,
    float* act0, float* aA, float* bA, float* aO, float* bO,
    float* r_a, float* r_o, unsigned* bar)
{
    int g = blockIdx.x * 256 + threadIdx.x;
    int T = gridDim.x * 256;
    for (int i = g; i < 32 * 2048; i += T) act0[i] = start_state[i & 2047];
    for (int i = g; i < 32 * 512; i += T) { aA[i] = 0.f; bA[i] = 0.f; aO[i] = 0.f; bO[i] = 0.f; }
    for (int i = g; i < 512; i += T) {
        float da = fminf(fmaxf(dec_a[i], 0.f), 15.f);
        float dv = fminf(fmaxf(dec_o[i], 0.f), 15.f);
        r_a[i] = __expf(-da);
        r_o[i] = __expf(-dv);
    }
    if (g < 2048) bar[g] = 0u;
}

// ------------------------------------------------- kv = x^T @ W_kv + b_kv (fp32 out)
__global__ __launch_bounds__(256) void k_gemm_xT(
    const float* __restrict__ x, const float* __restrict__ Wkv,
    const float* __restrict__ bkv, float* __restrict__ out)
{
    __shared__ float As[16 * 68];
    __shared__ float Bs[16 * 132];
    int tid = threadIdx.x;
    int tn = tid & 15, tm = tid >> 4;
    int n0 = blockIdx.x * 128;
    int r0 = blockIdx.y * 64;
    int b = r0 >> 10;
    int nrow0 = r0 & 1023;
    const float* xb = x + (size_t)b * 512 * 1024;
    float acc[4][8];
#pragma unroll
    for (int i = 0; i < 4; ++i)
#pragma unroll
        for (int j = 0; j < 8; ++j) acc[i][j] = 0.f;

    for (int k0 = 0; k0 < 512; k0 += 16) {
        __syncthreads();
#pragma unroll
        for (int l = 0; l < 4; ++l) {
            int i = tid + l * 256;
            int nn = i & 63, kk = i >> 6;
            As[kk * 68 + nn] = xb[(size_t)(k0 + kk) * 1024 + nrow0 + nn];
        }
#pragma unroll
        for (int l = 0; l < 8; ++l) {
            int i = tid + l * 256;
            int n = i & 127, kk = i >> 7;
            Bs[kk * 132 + n] = Wkv[(size_t)(k0 + kk) * 512 + n0 + n];
        }
        __syncthreads();
#pragma unroll
        for (int k = 0; k < 16; ++k) {
            float4 a4 = *(const float4*)&As[k * 68 + tm * 4];
            float4 b0 = *(const float4*)&Bs[k * 132 + tn * 8];
            float4 b1 = *(const float4*)&Bs[k * 132 + tn * 8 + 4];
            float av[4] = {a4.x, a4.y, a4.z, a4.w};
            float bv[8] = {b0.x, b0.y, b0.z, b0.w, b1.x, b1.y, b1.z, b1.w};
#pragma unroll
            for (int i = 0; i < 4; ++i)
#pragma unroll
                for (int j = 0; j < 8; ++j) acc[i][j] += av[i] * bv[j];
        }
    }
#pragma unroll
    for (int i = 0; i < 4; ++i) {
        int r = r0 + tm * 4 + i;
        int c = n0 + tn * 8;
        float* orow = out + (size_t)r * 512 + c;
#pragma unroll
        for (int j = 0; j < 8; ++j) orow[j] = acc[i][j] + bkv[c + j];
    }
}

// ------------------------------------------------ generic fp32 GEMM -> bf16 out, K=512
__global__ __launch_bounds__(256) void k_gemm_AB(
    const float* __restrict__ A, int lda,
    const float* __restrict__ B, int ldb,
    const float* __restrict__ bias,
    u16* __restrict__ out, int N)
{
    __shared__ float As[16 * 68];
    __shared__ float Bs[16 * 132];
    int tid = threadIdx.x;
    int tn = tid & 15, tm = tid >> 4;
    int n0 = blockIdx.x * 128;
    int r0 = blockIdx.y * 64;
    float acc[4][8];
#pragma unroll
    for (int i = 0; i < 4; ++i)
#pragma unroll
        for (int j = 0; j < 8; ++j) acc[i][j] = 0.f;

    for (int k0 = 0; k0 < 512; k0 += 16) {
        __syncthreads();
#pragma unroll
        for (int l = 0; l < 4; ++l) {
            int i = tid + l * 256;
            int kk = i & 15, m = i >> 4;
            As[kk * 68 + m] = A[(size_t)(r0 + m) * lda + k0 + kk];
        }
#pragma unroll
        for (int l = 0; l < 8; ++l) {
            int i = tid + l * 256;
            int n = i & 127, kk = i >> 7;
            Bs[kk * 132 + n] = B[(size_t)(k0 + kk) * ldb + n0 + n];
        }
        __syncthreads();
#pragma unroll
        for (int k = 0; k < 16; ++k) {
            float4 a4 = *(const float4*)&As[k * 68 + tm * 4];
            float4 b0 = *(const float4*)&Bs[k * 132 + tn * 8];
            float4 b1 = *(const float4*)&Bs[k * 132 + tn * 8 + 4];
            float av[4] = {a4.x, a4.y, a4.z, a4.w};
            float bv[8] = {b0.x, b0.y, b0.z, b0.w, b1.x, b1.y, b1.z, b1.w};
#pragma unroll
            for (int i = 0; i < 4; ++i)
#pragma unroll
                for (int j = 0; j < 8; ++j) acc[i][j] += av[i] * bv[j];
        }
    }
#pragma unroll
    for (int i = 0; i < 4; ++i) {
        int r = r0 + tm * 4 + i;
        int c = n0 + tn * 8;
        float vv[8];
#pragma unroll
        for (int j = 0; j < 8; ++j) vv[j] = acc[i][j] + (bias ? bias[c + j] : 0.f);
        unsigned int w0 = (unsigned int)f2bf(vv[0]) | ((unsigned int)f2bf(vv[1]) << 16);
        unsigned int w1 = (unsigned int)f2bf(vv[2]) | ((unsigned int)f2bf(vv[3]) << 16);
        unsigned int w2 = (unsigned int)f2bf(vv[4]) | ((unsigned int)f2bf(vv[5]) << 16);
        unsigned int w3 = (unsigned int)f2bf(vv[6]) | ((unsigned int)f2bf(vv[7]) << 16);
        *(uint4*)&out[(size_t)r * N + c] = make_uint4(w0, w1, w2, w3);
    }
}

// ------------------------------------------------- in-place LN over kv rows (512 wide)
__global__ __launch_bounds__(256) void k_ln_kv(
    float* __restrict__ kv, const float* __restrict__ g, const float* __restrict__ be)
{
    int tid = threadIdx.x;
    int lane = tid & 63;
    int row = blockIdx.x * 4 + (tid >> 6);
    float* p = kv + (size_t)row * 512 + lane * 8;
    float4 u0 = *(float4*)p;
    float4 u1 = *(float4*)(p + 4);
    float v[8] = {u0.x, u0.y, u0.z, u0.w, u1.x, u1.y, u1.z, u1.w};
    float s = 0.f, s2 = 0.f;
#pragma unroll
    for (int i = 0; i < 8; ++i) { s += v[i]; s2 += v[i] * v[i]; }
#pragma unroll
    for (int off = 32; off >= 1; off >>= 1) {
        s += __shfl_xor(s, off, 64);
        s2 += __shfl_xor(s2, off, 64);
    }
    float m = s * (1.f / 512.f);
    float var = s2 * (1.f / 512.f) - m * m;
    float rs = rsqrtf(var + 1e-5f);
    const float* gp = g + lane * 8;
    const float* bp = be + lane * 8;
#pragma unroll
    for (int i = 0; i < 8; ++i) v[i] = (v[i] - m) * rs * gp[i] + bp[i];
    *(float4*)p = make_float4(v[0], v[1], v[2], v[3]);
    *(float4*)(p + 4) = make_float4(v[4], v[5], v[6], v[7]);
}

// ---------------------------------------------- bias-fold: out[j] = vin@B[:,j] + badd[j]
__global__ __launch_bounds__(256) void k_bvec(
    const float* __restrict__ vin, const float* __restrict__ B, int ldb,
    const float* __restrict__ badd, float* __restrict__ out, int Nj)
{
    int j = blockIdx.x * 256 + threadIdx.x;
    if (j >= Nj) return;
    float s = 0.f;
    for (int e = 0; e < 512; ++e) s += vin[e] * B[(size_t)e * ldb + j];
    out[j] = s + badd[j];
}

// ---------------------------------------------- f32 -> bf16 convert
__global__ __launch_bounds__(256) void k_convert(
    const float* __restrict__ src, u16* __restrict__ dst, int n)
{
    int g = blockIdx.x * 256 + threadIdx.x;
    int T = gridDim.x * 256;
    for (int i = g; i < n; i += T) dst[i] = f2bf(src[i]);
}

// ---------------------------------------------- W_out [512][1000] -> WT [1000][512] bf16
__global__ __launch_bounds__(256) void k_transpose_wout(
    const float* __restrict__ W, u16* __restrict__ WT)
{
    int j = blockIdx.x * 256 + threadIdx.x;
    if (j >= 1000) return;
    for (int k = 0; k < 512; ++k) WT[(size_t)j * 512 + k] = f2bf(W[(size_t)k * 1000 + j]);
}

// ---------------------------------------------- V [b,n,h,d] -> VT [b,h,d,n] bf16
__global__ __launch_bounds__(256) void k_transpose_v(
    const u16* __restrict__ V, u16* __restrict__ VT)
{
    int bh = blockIdx.x;
    int b = bh >> 3, h = bh & 7;
    int tid = threadIdx.x;
    const u16* src = V + (size_t)b * 1024 * 512 + h * 64;
    u16* dst = VT + (size_t)bh * 64 * 1024;
    int n0 = tid * 4;
    for (int d = 0; d < 64; ++d) {
        u16 a0 = src[(size_t)(n0 + 0) * 512 + d];
        u16 a1 = src[(size_t)(n0 + 1) * 512 + d];
        u16 a2 = src[(size_t)(n0 + 2) * 512 + d];
        u16 a3 = src[(size_t)(n0 + 3) * 512 + d];
        uint2 w = make_uint2((unsigned)a0 | ((unsigned)a1 << 16),
                             (unsigned)a2 | ((unsigned)a3 << 16));
        *(uint2*)&dst[(size_t)d * 1024 + n0] = w;
    }
}

// ================================================================ persistent loop
#define NBLK 1024

struct LoopP {
    const u16* Wqq; const float* bqq;
    const u16* K;   const u16* VT;
    const u16* Wfull; const float* bcomb;
    const u16* W1; const float* b1;
    const u16* W2; const float* b2;
    const u16* WoutT; const float* bout;
    const int* idxA; const int* idxO;
    const float* r_a; const float* r_o;
    float* aA0; float* aA1; float* bA0; float* bA1;
    float* aO0; float* aO1; float* bO0; float* bO1;
    float* act0; float* act1;
    float* pvp; float* mz;                 // [4][256][64] ; [4][256] float2 (m,z)
    float* attn_f; float* actR;            // [32][512] ; [32][2048]
    float* h_pre; float* hpm; float* t1;
    float* out;
    const float* gsyn; const float* besyn; const float* gpm; const float* bepm;
    unsigned* bar;
};

union Smem {
    struct { float sA[512]; float qh[64]; float sc[256]; float red[512]; } at; // 5376 B
    struct { float mzs[64]; float arow[512]; } b2;                             // 2304 B
    struct { float Al[32 * 36]; } sk;                                          // 4608 B
    struct { float red[16]; } gl;
    struct { float sO[512]; float red[8]; } pr;                                // 2080 B
};

// Tree grid barrier (r6-proven): 16 arrival counters -> 1 root -> 32 gen lines.
__device__ __forceinline__ void gridbar(unsigned* bar)
{
    __syncthreads();
    if (threadIdx.x == 0) {
        int blk = blockIdx.x;
        unsigned* cnt1 = bar + ((blk >> 6) << 5);          // 16 lines
        unsigned* cnt2 = bar + (16 << 5);
        unsigned* genp = bar + ((17 + (blk & 31)) << 5);   // 32 lines
        unsigned g = __hip_atomic_load(genp, __ATOMIC_RELAXED, __HIP_MEMORY_SCOPE_AGENT);
        asm volatile("s_waitcnt vmcnt(0)" ::: "memory");   // g settled before arrival
        unsigned a = __hip_atomic_fetch_add(cnt1, 1u, __ATOMIC_RELAXED, __HIP_MEMORY_SCOPE_AGENT);
        if (a == 63u) {
            __hip_atomic_store(cnt1, 0u, __ATOMIC_RELAXED, __HIP_MEMORY_SCOPE_AGENT);
            asm volatile("s_waitcnt vmcnt(0)" ::: "memory");  // reset lands first
            unsigned a2 = __hip_atomic_fetch_add(cnt2, 1u, __ATOMIC_RELAXED, __HIP_MEMORY_SCOPE_AGENT);
            if (a2 == 15u) {
                __hip_atomic_store(cnt2, 0u, __ATOMIC_RELAXED, __HIP_MEMORY_SCOPE_AGENT);
                asm volatile("s_waitcnt vmcnt(0)" ::: "memory");
#pragma unroll
                for (int r = 0; r < 32; ++r)
                    __hip_atomic_store(bar + ((17 + r) << 5), g + 1u,
                                       __ATOMIC_RELAXED, __HIP_MEMORY_SCOPE_AGENT);
            }
        }
        unsigned cur;
        do {
            cur = __hip_atomic_load(genp, __ATOMIC_RELAXED, __HIP_MEMORY_SCOPE_AGENT);
            if (cur != g) break;
            __builtin_amdgcn_s_sleep(2);
        } while (true);
        asm volatile("" ::: "memory");
    }
    __syncthreads();
}

__device__ __forceinline__ void red2(float& a, float& b, float* red, int tid)
{
#pragma unroll
    for (int off = 32; off >= 1; off >>= 1) {
        a += __shfl_xor(a, off, 64);
        b += __shfl_xor(b, off, 64);
    }
    __syncthreads();
    if ((tid & 63) == 0) { red[(tid >> 6) * 2] = a; red[(tid >> 6) * 2 + 1] = b; }
    __syncthreads();
    float sa = 0.f, sb = 0.f;
#pragma unroll
    for (int w = 0; w < 8; ++w) { sa += red[2 * w]; sb += red[2 * w + 1]; }
    a = sa; b = sb;
}

__global__ __launch_bounds__(512, 8) void k_loop(LoopP P)
{
    __shared__ Smem s;
    const int tid = threadIdx.x;
    const int blk = blockIdx.x;
    const int lane = tid & 63;
    const int wav = tid >> 6;

    for (int t = 0; t < 50; ++t) {
        const float* actprev = (t & 1) ? P.act1 : P.act0;
        float*       actnext = (t & 1) ? P.act0 : P.act1;
        const float* aAp = (t & 1) ? P.aA1 : P.aA0;  float* aAc = (t & 1) ? P.aA0 : P.aA1;
        const float* bAp = (t & 1) ? P.bA1 : P.bA0;  float* bAc = (t & 1) ? P.bA0 : P.bA1;
        const float* aOp = (t & 1) ? P.aO1 : P.aO0;  float* aOc = (t & 1) ? P.aO0 : P.aO1;
        const float* bOp = (t & 1) ? P.bO1 : P.bO0;  float* bOc = (t & 1) ? P.bO0 : P.bO1;

        __syncthreads();   // protect LDS union against previous phase readers

        // ============ phase B : 4-way-split attention + zero scratch + actR ==
        {
            int bh = blk >> 2, p = blk & 3;      // 256 (b,h) groups x 4 n-parts
            int b = bh >> 3, h = bh & 7;
            // zero per-step scratch with 16B stores: 1024 blk x 64 f4 = 262144 f
            if (tid < 64) {
                int g4 = blk * 64 + tid;
                fv4 zz = {0.f, 0.f, 0.f, 0.f};
                if (g4 < 32768) cstore4(&P.h_pre[g4 * 4], zz);
                else if (g4 < 49152) cstore4(&P.t1[(g4 - 32768) * 4], zz);
                else cstore4(&actnext[(g4 - 49152) * 4], zz);
            }
            // p==0 blocks also precompute actR[b] slice (relu(act+b2), once/step)
            if (p == 0 && tid >= 64 && tid < 128) {
                int i4 = (h * 64 + (tid - 64)) * 4;
                fv4 v;
                cload(v, &actprev[b * 2048 + i4]);
                cwait1(v);
                if (t > 0) {
                    float4 b4 = *(const float4*)&P.b2[i4];
                    v.x = fmaxf(0.f, v.x + b4.x);
                    v.y = fmaxf(0.f, v.y + b4.y);
                    v.z = fmaxf(0.f, v.z + b4.z);
                    v.w = fmaxf(0.f, v.w + b4.w);
                }
                cstore4(&P.actR[b * 2048 + i4], v);
            }
            {   // syncA (32 dup writers per (b,j) -- identical values, benign)
                int j = tid;
                int ia = P.idxA[j];
                float v = aload(&actprev[b * 2048 + ia]);
                if (t > 0) v = fmaxf(0.f, v + P.b2[ia]);
                float r = P.r_a[j];
                float a = r * aAp[b * 512 + j] + v * v;
                float bb = r * bAp[b * 512 + j] + 1.f;
                aAc[b * 512 + j] = a; bAc[b * 512 + j] = bb;
                s.at.sA[j] = a * rsqrtf(bb);
            }
            __syncthreads();
            {   // qh = sA @ Wqq slice  (8-way K split)
                int d = tid & 63, kg = tid >> 6;
                const u16* wp = P.Wqq + (size_t)(kg * 64) * 512 + h * 64 + d;
                const float* ap = s.at.sA + kg * 64;
                float pq = 0.f;
#pragma unroll 16
                for (int k = 0; k < 64; ++k) pq += ap[k] * bf2f(wp[(size_t)k * 512]);
                s.at.red[tid] = pq;
            }
            __syncthreads();
            if (tid < 64) {
                float q = P.bqq[h * 64 + tid];
#pragma unroll
                for (int g2 = 0; g2 < 8; ++g2) q += s.at.red[g2 * 64 + tid];
                s.at.qh[tid] = q;
            }
            __syncthreads();
            // scores for this part's 256 rows (1 row per thread, tid<256)
            if (tid < 256) {
                const u16* Kbh = P.K + (size_t)b * 1024 * 512 + h * 64;
                const uv4* kp = (const uv4*)(Kbh + (size_t)(p * 256 + tid) * 512);
                uv4 u[8];
#pragma unroll
                for (int i = 0; i < 8; ++i) u[i] = __builtin_nontemporal_load(kp + i);
                float dot = 0.f;
#pragma unroll
                for (int i = 0; i < 8; ++i) {
                    float4 q0 = *(float4*)&s.at.qh[i * 8];
                    float4 q1 = *(float4*)&s.at.qh[i * 8 + 4];
                    dot += q0.x * bflo(u[i].x) + q0.y * bfhi(u[i].x)
                         + q0.z * bflo(u[i].y) + q0.w * bfhi(u[i].y)
                         + q1.x * bflo(u[i].z) + q1.y * bfhi(u[i].z)
                         + q1.z * bflo(u[i].w) + q1.w * bfhi(u[i].w);
                }
                s.at.sc[tid] = dot * 0.125f;
            }
            __syncthreads();
            // local max over 256
            float mv = (tid < 256) ? s.at.sc[tid] : -1e30f;
#pragma unroll
            for (int off = 32; off >= 1; off >>= 1) mv = fmaxf(mv, __shfl_xor(mv, off, 64));
            if (lane == 0) s.at.red[wav] = mv;
            __syncthreads();
            float mloc = s.at.red[0];
#pragma unroll
            for (int w = 1; w < 8; ++w) mloc = fmaxf(mloc, s.at.red[w]);
            // exp + local sum
            float ev = 0.f;
            if (tid < 256) {
                ev = __expf(s.at.sc[tid] - mloc);
                s.at.sc[tid] = ev;
            }
            float zv = ev;
#pragma unroll
            for (int off = 32; off >= 1; off >>= 1) zv += __shfl_xor(zv, off, 64);
            __syncthreads();
            if (lane == 0) s.at.red[wav] = zv;
            __syncthreads();
            float Zloc = 0.f;
#pragma unroll
            for (int w = 0; w < 8; ++w) Zloc += s.at.red[w];
            __syncthreads();   // red reads done before PV rewrites red
            // PV over this part's 256 rows: 8 groups x 32 rows
            {
                int d = tid & 63, ng = tid >> 6;
                const uv4* vp = (const uv4*)(P.VT
                    + ((size_t)bh * 64 + d) * 1024 + p * 256 + ng * 32);
                float acc = 0.f;
#pragma unroll
                for (int i = 0; i < 4; ++i) {
                    uv4 u = __builtin_nontemporal_load(vp + i);
                    const float* so = s.at.sc + ng * 32 + i * 8;
                    acc += so[0] * bflo(u.x) + so[1] * bfhi(u.x)
                         + so[2] * bflo(u.y) + so[3] * bfhi(u.y)
                         + so[4] * bflo(u.z) + so[5] * bfhi(u.z)
                         + so[6] * bflo(u.w) + so[7] * bfhi(u.w);
                }
                s.at.red[tid] = acc;
            }
            __syncthreads();
            if (tid < 64) {
                float a = 0.f;
#pragma unroll
                for (int g2 = 0; g2 < 8; ++g2) a += s.at.red[g2 * 64 + tid];
                s.at.qh[tid] = a;                  // reuse qh as pv staging
            }
            __syncthreads();
            if (tid < 16) {                        // 16B coherent pv write
                fv4 v = *(fv4*)&s.at.qh[tid * 4];
                cstore4(&P.pvp[((size_t)p * 256 + bh) * 64 + tid * 4], v);
            }
            if (tid == 0) {                        // 8B coherent (m,z) write
                fv2 v; v.x = mloc; v.y = Zloc;
                cstore2(&P.mz[(p * 256 + bh) * 2], v);
            }
        }
        gridbar(P.bar);

        // ============ phase B2 : combine softmax partials -> attn_f (32 blocks)
        if (blk < 32) {
            int b = blk;
            if (tid < 32) {        // mz -> LDS: tid = p*8 + h
                int p = tid >> 3, h = tid & 7;
                fv2 v;
                cload2(v, &P.mz[(p * 256 + b * 8 + h) * 2]);
                cwaitf2(v);
                s.b2.mzs[tid * 2] = v.x;
                s.b2.mzs[tid * 2 + 1] = v.y;
            }
            __syncthreads();
            int h = tid >> 6, d = tid & 63;
            int rh = b * 8 + h;
            float m0 = s.b2.mzs[(0 * 8 + h) * 2], z0 = s.b2.mzs[(0 * 8 + h) * 2 + 1];
            float m1 = s.b2.mzs[(1 * 8 + h) * 2], z1 = s.b2.mzs[(1 * 8 + h) * 2 + 1];
            float m2 = s.b2.mzs[(2 * 8 + h) * 2], z2 = s.b2.mzs[(2 * 8 + h) * 2 + 1];
            float m3 = s.b2.mzs[(3 * 8 + h) * 2], z3 = s.b2.mzs[(3 * 8 + h) * 2 + 1];
            float M = fmaxf(fmaxf(m0, m1), fmaxf(m2, m3));
            float e0 = __expf(m0 - M), e1 = __expf(m1 - M);
            float e2 = __expf(m2 - M), e3 = __expf(m3 - M);
            float Zinv = 1.f / (z0 * e0 + z1 * e1 + z2 * e2 + z3 * e3);
            float acc = aload(&P.pvp[((size_t)0 * 256 + rh) * 64 + d]) * e0
                      + aload(&P.pvp[((size_t)1 * 256 + rh) * 64 + d]) * e1
                      + aload(&P.pvp[((size_t)2 * 256 + rh) * 64 + d]) * e2
                      + aload(&P.pvp[((size_t)3 * 256 + rh) * 64 + d]) * e3;
            s.b2.arow[tid] = acc * Zinv;
            __syncthreads();
            if (tid < 128) {
                fv4 v = *(fv4*)&s.b2.arow[tid * 4];
                cstore4(&P.attn_f[b * 512 + tid * 4], v);
            }
        }
        gridbar(P.bar);

        // ============ phase C : h_pre = [attn_f|actR] @ Wfull (2560x4096) ====
        // r7 splitK structure: 16 kb x 64 jb, k-range 160, tile 32; staging is
        // now two plain wide-load streams (attn_f / actR).
        {
            int kb = blk >> 6, jb = blk & 63;
            int j = jb * 64 + (tid & 63);
            int rg = tid >> 6;             // 8 groups x 4 rows
            int kbeg = kb * 160;
            float a0 = 0.f, a1 = 0.f, a2 = 0.f, a3 = 0.f;
            for (int k0 = kbeg; k0 < kbeg + 160; k0 += 32) {
                __syncthreads();
                if (tid < 256) {           // stage 32k x 32r as f4 along k
                    int k4 = (tid & 7) * 4, r = tid >> 3;
                    int kk = k0 + k4;
                    fv4 v;
                    if (kk < 512) {        // tile-uniform branch (k0 mult of 32)
                        cload(v, &P.attn_f[r * 512 + kk]);
                        cwait1(v);
                    } else {
                        cload(v, &P.actR[r * 2048 + kk - 512]);
                        cwait1(v);
                    }
                    s.sk.Al[(k4 + 0) * 36 + r] = v.x;
                    s.sk.Al[(k4 + 1) * 36 + r] = v.y;
                    s.sk.Al[(k4 + 2) * 36 + r] = v.z;
                    s.sk.Al[(k4 + 3) * 36 + r] = v.w;
                }
                __syncthreads();
                const u16* wp = P.Wfull + (size_t)k0 * 4096 + j;
#pragma unroll 32
                for (int k = 0; k < 32; ++k) {
                    float w = bf2f(wp[(size_t)k * 4096]);
                    float4 a = *(const float4*)&s.sk.Al[k * 36 + rg * 4];
                    a0 += a.x * w; a1 += a.y * w; a2 += a.z * w; a3 += a.w * w;
                }
            }
            int r0 = rg * 4;
            atomicAdd(&P.h_pre[(size_t)(r0 + 0) * 4096 + j], a0);
            atomicAdd(&P.h_pre[(size_t)(r0 + 1) * 4096 + j], a1);
            atomicAdd(&P.h_pre[(size_t)(r0 + 2) * 4096 + j], a2);
            atomicAdd(&P.h_pre[(size_t)(r0 + 3) * 4096 + j], a3);
        }
        gridbar(P.bar);

        // ============ phase D : GLU + double LayerNorm (32 blocks, f4) =====
        if (blk < 32) {
            const float* hr = P.h_pre + (size_t)blk * 4096;
            int i4 = tid * 4;
            fv4 av, gv;
            cload(av, hr + i4);
            cload(gv, hr + 2048 + i4);
            cwait2(av, gv);
            float4 bc1 = *(const float4*)&P.bcomb[i4];
            float4 bc2 = *(const float4*)&P.bcomb[2048 + i4];
            fv4 z;
            z.x = (av.x + bc1.x) / (1.f + __expf(-(gv.x + bc2.x)));
            z.y = (av.y + bc1.y) / (1.f + __expf(-(gv.y + bc2.y)));
            z.z = (av.z + bc1.z) / (1.f + __expf(-(gv.z + bc2.z)));
            z.w = (av.w + bc1.w) / (1.f + __expf(-(gv.w + bc2.w)));
            float sa = z.x + z.y + z.z + z.w;
            float sb = z.x * z.x + z.y * z.y + z.z * z.z + z.w * z.w;
            red2(sa, sb, s.gl.red, tid);
            float m1 = sa * (1.f / 2048.f);
            float v1 = sb * (1.f / 2048.f) - m1 * m1;
            float rs1 = rsqrtf(v1 + 1e-5f);
            float4 gs = *(const float4*)&P.gsyn[i4];
            float4 bs = *(const float4*)&P.besyn[i4];
            z.x = (z.x - m1) * rs1 * gs.x + bs.x;
            z.y = (z.y - m1) * rs1 * gs.y + bs.y;
            z.z = (z.z - m1) * rs1 * gs.z + bs.z;
            z.w = (z.w - m1) * rs1 * gs.w + bs.w;
            float ta = z.x + z.y + z.z + z.w;
            float tb = z.x * z.x + z.y * z.y + z.z * z.z + z.w * z.w;
            red2(ta, tb, s.gl.red, tid);
            float m2 = ta * (1.f / 2048.f);
            float v2 = tb * (1.f / 2048.f) - m2 * m2;
            float rs2 = rsqrtf(v2 + 1e-5f);
            float4 gp = *(const float4*)&P.gpm[i4];
            float4 bp = *(const float4*)&P.bepm[i4];
            fv4 o;
            o.x = (z.x - m2) * rs2 * gp.x + bp.x;
            o.y = (z.y - m2) * rs2 * gp.y + bp.y;
            o.z = (z.z - m2) * rs2 * gp.z + bp.z;
            o.w = (z.w - m2) * rs2 * gp.w + bp.w;
            cstore4(&P.hpm[(size_t)blk * 2048 + i4], o);
        }
        gridbar(P.bar);

        // ============ phase E : t1 = hpm @ W1 (2048x2048, splitK=32) =======
        {
            int kb = blk >> 5, jb = blk & 31;
            int j = jb * 64 + (tid & 63);
            int rg = tid >> 6;
            int kbeg = kb * 64;
            float a0 = 0.f, a1 = 0.f, a2 = 0.f, a3 = 0.f;
            for (int k0 = kbeg; k0 < kbeg + 64; k0 += 32) {
                __syncthreads();
                if (tid < 256) {
                    int k4 = (tid & 7) * 4, r = tid >> 3;
                    fv4 v;
                    cload(v, &P.hpm[r * 2048 + k0 + k4]);
                    cwait1(v);
                    s.sk.Al[(k4 + 0) * 36 + r] = v.x;
                    s.sk.Al[(k4 + 1) * 36 + r] = v.y;
                    s.sk.Al[(k4 + 2) * 36 + r] = v.z;
                    s.sk.Al[(k4 + 3) * 36 + r] = v.w;
                }
                __syncthreads();
                const u16* wp = P.W1 + (size_t)k0 * 2048 + j;
#pragma unroll 32
                for (int k = 0; k < 32; ++k) {
                    float w = bf2f(wp[(size_t)k * 2048]);
                    float4 a = *(const float4*)&s.sk.Al[k * 36 + rg * 4];
                    a0 += a.x * w; a1 += a.y * w; a2 += a.z * w; a3 += a.w * w;
                }
            }
            int r0 = rg * 4;
            atomicAdd(&P.t1[(r0 + 0) * 2048 + j], a0);
            atomicAdd(&P.t1[(r0 + 1) * 2048 + j], a1);
            atomicAdd(&P.t1[(r0 + 2) * 2048 + j], a2);
            atomicAdd(&P.t1[(r0 + 3) * 2048 + j], a3);
        }
        gridbar(P.bar);

        // ============ phase F : actnext = relu(t1+b1) @ W2 (splitK=32) =====
        {
            int kb = blk >> 5, jb = blk & 31;
            int j = jb * 64 + (tid & 63);
            int rg = tid >> 6;
            int kbeg = kb * 64;
            float a0 = 0.f, a1 = 0.f, a2 = 0.f, a3 = 0.f;
            for (int k0 = kbeg; k0 < kbeg + 64; k0 += 32) {
                __syncthreads();
                if (tid < 256) {
                    int k4 = (tid & 7) * 4, r = tid >> 3;
                    int kk = k0 + k4;
                    fv4 v;
                    cload(v, &P.t1[r * 2048 + kk]);
                    cwait1(v);
                    float4 b4 = *(const float4*)&P.b1[kk];
                    s.sk.Al[(k4 + 0) * 36 + r] = fmaxf(0.f, v.x + b4.x);
                    s.sk.Al[(k4 + 1) * 36 + r] = fmaxf(0.f, v.y + b4.y);
                    s.sk.Al[(k4 + 2) * 36 + r] = fmaxf(0.f, v.z + b4.z);
                    s.sk.Al[(k4 + 3) * 36 + r] = fmaxf(0.f, v.w + b4.w);
                }
                __syncthreads();
                const u16* wp = P.W2 + (size_t)k0 * 2048 + j;
#pragma unroll 32
                for (int k = 0; k < 32; ++k) {
                    float w = bf2f(wp[(size_t)k * 2048]);
                    float4 a = *(const float4*)&s.sk.Al[k * 36 + rg * 4];
                    a0 += a.x * w; a1 += a.y * w; a2 += a.z * w; a3 += a.w * w;
                }
            }
            int r0 = rg * 4;
            atomicAdd(&actnext[(r0 + 0) * 2048 + j], a0);
            atomicAdd(&actnext[(r0 + 1) * 2048 + j], a1);
            atomicAdd(&actnext[(r0 + 2) * 2048 + j], a2);
            atomicAdd(&actnext[(r0 + 3) * 2048 + j], a3);
        }
        gridbar(P.bar);

        // ============ phase HI : syncO + pred (transposed Wout) + entropy ==
        if (blk < 32) {
            int b = blk;
            {   // syncO (block-exclusive aO state)
                int j2 = tid;
                int io = P.idxO[j2];
                float v = fmaxf(0.f, aload(&actnext[b * 2048 + io]) + P.b2[io]);
                float r = P.r_o[j2];
                float a = r * aOp[b * 512 + j2] + v * v;
                float bb = r * bOp[b * 512 + j2] + 1.f;
                aOc[b * 512 + j2] = a; bOc[b * 512 + j2] = bb;
                float sy = a * rsqrtf(bb);
                s.pr.sO[j2] = sy;
                if (t == 49) P.out[1603200 + b * 512 + j2] = sy;
            }
            __syncthreads();
            bool has1 = tid < 488;       // tid+512 < 1000
            float p0, p1 = -1e30f;
            {
                const uint4* wp = (const uint4*)(P.WoutT + (size_t)tid * 512);
                float acc = 0.f;
#pragma unroll 16
                for (int i = 0; i < 64; ++i) {
                    uint4 u = wp[i];
                    const float* so = s.pr.sO + i * 8;
                    acc += so[0] * bflo(u.x) + so[1] * bfhi(u.x)
                         + so[2] * bflo(u.y) + so[3] * bfhi(u.y)
                         + so[4] * bflo(u.z) + so[5] * bfhi(u.z)
                         + so[6] * bflo(u.w) + so[7] * bfhi(u.w);
                }
                p0 = acc + P.bout[tid];
            }
            if (has1) {
                const uint4* wp = (const uint4*)(P.WoutT + (size_t)(tid + 512) * 512);
                float acc = 0.f;
#pragma unroll 16
                for (int i = 0; i < 64; ++i) {
                    uint4 u = wp[i];
                    const float* so = s.pr.sO + i * 8;
                    acc += so[0] * bflo(u.x) + so[1] * bfhi(u.x)
                         + so[2] * bflo(u.y) + so[3] * bfhi(u.y)
                         + so[4] * bflo(u.z) + so[5] * bfhi(u.z)
                         + so[6] * bflo(u.w) + so[7] * bfhi(u.w);
                }
                p1 = acc + P.bout[tid + 512];
            }
            // entropy over {p0, p1}
            float mx = fmaxf(p0, p1);
#pragma unroll
            for (int off = 32; off >= 1; off >>= 1) mx = fmaxf(mx, __shfl_xor(mx, off, 64));
            __syncthreads();
            if (lane == 0) s.pr.red[wav] = mx;
            __syncthreads();
            mx = s.pr.red[0];
#pragma unroll
            for (int w = 1; w < 8; ++w) mx = fmaxf(mx, s.pr.red[w]);
            float zs = __expf(p0 - mx) + (has1 ? __expf(p1 - mx) : 0.f);
#pragma unroll
            for (int off = 32; off >= 1; off >>= 1) zs += __shfl_xor(zs, off, 64);
            __syncthreads();
            if (lane == 0) s.pr.red[wav] = zs;
            __syncthreads();
            float Z = 0.f;
#pragma unroll
            for (int w = 0; w < 8; ++w) Z += s.pr.red[w];
            float logZ = __logf(Z);
            float lp0 = p0 - mx - logZ;
            float se = __expf(lp0) * lp0;
            if (has1) { float lp1 = p1 - mx - logZ; se += __expf(lp1) * lp1; }
#pragma unroll
            for (int off = 32; off >= 1; off >>= 1) se += __shfl_xor(se, off, 64);
            __syncthreads();
            if (lane == 0) s.pr.red[wav] = se;
            __syncthreads();
            float S = 0.f;
#pragma unroll
            for (int w = 0; w < 8; ++w) S += s.pr.red[w];
            float ne = -S / logf(1000.0f);
            P.out[(size_t)b * 50000 + (size_t)tid * 50 + t] = p0;
            if (has1) P.out[(size_t)b * 50000 + (size_t)(tid + 512) * 50 + t] = p1;
            if (tid == 0) {
                P.out[1600000 + b * 100 + t] = ne;
                P.out[1600000 + b * 100 + 50 + t] = 1.f - ne;
            }
        }
        // no grid barrier before next step: B(t+1) reads actprev(=actnext(t),
        // F, 1 barrier back) and block-own aA state; actR/attn_f/pvp/mz are
        // rewritten >=3 barriers after their last step-t readers; h_pre/t1
        // zeroing targets last read in D(t)/F(t). HI outputs block-exclusive.
    }
}

// ================================================================ host launcher
extern "C" void kernel_launch(void* const* d_in, const int* in_sizes, int n_in,
                              void* d_out, int out_size, void* d_ws, size_t ws_size,
                              hipStream_t stream)
{
    const float* x      = (const float*)d_in[0];
    const float* W_kv   = (const float*)d_in[1];
    const float* b_kv   = (const float*)d_in[2];
    const float* g_kv   = (const float*)d_in[3];
    const float* be_kv  = (const float*)d_in[4];
    const float* W_q    = (const float*)d_in[5];
    const float* b_q    = (const float*)d_in[6];
    const float* W_in   = (const float*)d_in[7];
    const float* b_in   = (const float*)d_in[8];
    const float* W_ao   = (const float*)d_in[9];
    const float* b_ao   = (const float*)d_in[10];
    const float* W_syn  = (const float*)d_in[11];
    const float* b_syn  = (const float*)d_in[12];
    const float* g_syn  = (const float*)d_in[13];
    const float* be_syn = (const float*)d_in[14];
    const float* g_pm   = (const float*)d_in[15];
    const float* be_pm  = (const float*)d_in[16];
    const float* W1     = (const float*)d_in[17];
    const float* b1     = (const float*)d_in[18];
    const float* W2     = (const float*)d_in[19];
    const float* b2     = (const float*)d_in[20];
    const float* start_state  = (const float*)d_in[21];
    const float* decay_action = (const float*)d_in[22];
    const float* decay_out    = (const float*)d_in[23];
    const float* W_out  = (const float*)d_in[24];
    const float* b_out  = (const float*)d_in[25];
    const int* idx_action = (const int*)d_in[26];
    const int* idx_out    = (const int*)d_in[27];
    float* out = (float*)d_out;

    char* ws = (char*)d_ws;
    size_t off = 0;
    auto take = [&](size_t bytes) -> char* {
        char* p = ws + off;
        off += (bytes + 255) & ~(size_t)255;
        return p;
    };

    // region0: kv (fp32, precompute-only), later aliased by loop weights
    char* region0 = take(67108864);                 // 32768*512*4
    float* kv = (float*)region0;
    u16* W_full = (u16*)region0;                    // 2560 x 4096 bf16 = 20,971,520
    u16* W1b    = (u16*)(region0 + 20971520);       // 8,388,608
    u16* W2b    = (u16*)(region0 + 29360128);       // 8,388,608
    u16* WoutT  = (u16*)(region0 + 37748736);       // 1000 x 512 bf16 = 1,024,000
    u16* Wqqb   = (u16*)(region0 + 38772736);       // 524,288

    u16* K_bf = (u16*)take(33554432);
    u16* V_bf = (u16*)take(33554432);
    u16* V_T  = (u16*)take(33554432);
    float* b_qq   = (float*)take(2048);
    float* b_comb = (float*)take(16384);
    float* r_a = (float*)take(2048);
    float* r_o = (float*)take(2048);
    float* aA0 = (float*)take(65536);
    float* aA1 = (float*)take(65536);
    float* bA0 = (float*)take(65536);
    float* bA1 = (float*)take(65536);
    float* aO0 = (float*)take(65536);
    float* aO1 = (float*)take(65536);
    float* bO0 = (float*)take(65536);
    float* bO1 = (float*)take(65536);
    float* act0v = (float*)take(262144);
    float* act1v = (float*)take(262144);
    float* h_pre = (float*)take(524288);
    float* hpm   = (float*)take(262144);
    float* t1_pre = (float*)take(262144);
    float* pvp = (float*)take(262144);       // [4][256][64]
    float* mzB = (float*)take(8192);         // [4][256] float2
    float* attn_f = (float*)take(65536);     // [32][512]
    float* actR   = (float*)take(262144);    // [32][2048]
    unsigned* bar = (unsigned*)take(8192);
    (void)ws_size; (void)in_sizes; (void)n_in; (void)out_size;

    // ---------------- precompute ----------------
    k_init<<<256, 256, 0, stream>>>(start_state, decay_action, decay_out,
                                    act0v, aA0, bA0, aO0, bO0, r_a, r_o, bar);
    k_gemm_xT<<<dim3(4, 512), 256, 0, stream>>>(x, W_kv, b_kv, kv);
    k_ln_kv<<<8192, 256, 0, stream>>>(kv, g_kv, be_kv);
    k_gemm_AB<<<dim3(4, 512), 256, 0, stream>>>(kv, 512, W_in + 512, 1536, b_in + 512, K_bf, 512);
    k_gemm_AB<<<dim3(4, 512), 256, 0, stream>>>(kv, 512, W_in + 1024, 1536, b_in + 1024, V_bf, 512);
    k_transpose_v<<<256, 256, 0, stream>>>(V_bf, V_T);
    // kv now dead -> region0 reused for loop weights
    k_gemm_AB<<<dim3(4, 8), 256, 0, stream>>>(W_q, 512, W_in, 1536, nullptr, Wqqb, 512);
    k_gemm_AB<<<dim3(32, 8), 256, 0, stream>>>(W_ao, 512, W_syn, 4096, nullptr, W_full, 4096);
    k_bvec<<<2, 256, 0, stream>>>(b_q, W_in, 1536, b_in, b_qq, 512);
    k_bvec<<<16, 256, 0, stream>>>(b_ao, W_syn, 4096, b_syn, b_comb, 4096);
    k_convert<<<2048, 256, 0, stream>>>(W_syn + (size_t)512 * 4096, W_full + (size_t)512 * 4096, 2048 * 4096);
    k_convert<<<2048, 256, 0, stream>>>(W1, W1b, 2048 * 2048);
    k_convert<<<2048, 256, 0, stream>>>(W2, W2b, 2048 * 2048);
    k_transpose_wout<<<4, 256, 0, stream>>>(W_out, WoutT);

    // ---------------- recurrent loop: persistent kernel, plain launch ----------
    // 1024 blocks x 512 threads = exactly 4 blocks/CU (32 waves = HW max).
    LoopP p;
    p.Wqq = Wqqb; p.bqq = b_qq;
    p.K = K_bf;   p.VT = V_T;
    p.Wfull = W_full; p.bcomb = b_comb;
    p.W1 = W1b; p.b1 = b1;
    p.W2 = W2b; p.b2 = b2;
    p.WoutT = WoutT; p.bout = b_out;
    p.idxA = idx_action; p.idxO = idx_out;
    p.r_a = r_a; p.r_o = r_o;
    p.aA0 = aA0; p.aA1 = aA1; p.bA0 = bA0; p.bA1 = bA1;
    p.aO0 = aO0; p.aO1 = aO1; p.bO0 = bO0; p.bO1 = bO1;
    p.act0 = act0v; p.act1 = act1v;
    p.pvp = pvp; p.mz = mzB;
    p.attn_f = attn_f; p.actR = actR;
    p.h_pre = h_pre; p.hpm = hpm; p.t1 = t1_pre;
    p.out = out;
    p.gsyn = g_syn; p.besyn = be_syn; p.gpm = g_pm; p.bepm = be_pm;
    p.bar = bar;

    k_loop<<<dim3(NBLK), dim3(512), 0, stream>>>(p);
}